// Round 10
// baseline (130.467 us; speedup 1.0000x reference)
//
#include <hip/hip_runtime.h>
#include <hip/hip_bf16.h>
#include <stdint.h>

// ---------------- problem constants ----------------
#define BATCH  4096
#define IN_DIM 1024
#define HS     1024
#define K_DIM  2048                 // IN + HS
#define N_DIM  4096                 // 4 gates * HS (gate-interleaved, see pack)
#define BK 64
#define NKT (K_DIM / BK)            // 32 K-tiles
#define HALF_BYTES 16384            // 128 rows x 64 cols x 2B
#define TPB_BYTES  (NKT * HALF_BYTES)   // bytes per 128-row panel, all K

typedef __bf16 bf16x8 __attribute__((ext_vector_type(8)));
typedef float  f32x4  __attribute__((ext_vector_type(4)));

// ---------------- helpers ----------------
__device__ __forceinline__ unsigned short f2bf(float f) {
    union { float f; uint32_t u; } a; a.f = f;
    uint32_t r = a.u + 0x7FFF + ((a.u >> 16) & 1);   // RNE
    return (unsigned short)(r >> 16);
}
__device__ __forceinline__ uint32_t pk2(float a, float b) {
    return (uint32_t)f2bf(a) | ((uint32_t)f2bf(b) << 16);
}

__device__ __forceinline__ void load16_lds(const void* g, void* l) {
    __builtin_amdgcn_global_load_lds(
        (const __attribute__((address_space(1))) uint32_t*)g,
        (__attribute__((address_space(3))) uint32_t*)(uintptr_t)l,
        16, 0, 0);
}
// stage one 16KB half-tile: 512 threads x 16B x 2 rounds (2 vmem insts)
__device__ __forceinline__ void stage16k(const char* g, char* l, int wid, int lane) {
    load16_lds(g + wid * 1024 + lane * 16,        l + wid * 1024);
    load16_lds(g + 8192 + wid * 1024 + lane * 16, l + 8192 + wid * 1024);
}

__device__ __forceinline__ float sigf(float x)  { return 1.0f / (1.0f + __expf(-x)); }
__device__ __forceinline__ float tanhf_(float x){ return 1.0f - 2.0f / (__expf(2.0f * x) + 1.0f); }

#define BAR()   __builtin_amdgcn_s_barrier()
#define DSB()   __builtin_amdgcn_sched_barrier(0)
#define PRIO(x) __builtin_amdgcn_s_setprio(x)
#define VMC(n)  asm volatile("s_waitcnt vmcnt(" #n ")" ::: "memory")

// 4 A-reads of one 32-row quad from LDS (swizzled): d[mf*2+ks]
__device__ __forceinline__ void rdA4(bf16x8 (&d)[4], const char* base, int kb0, int kb1) {
    d[0] = *(const bf16x8*)(base + kb0);
    d[1] = *(const bf16x8*)(base + kb1);
    d[2] = *(const bf16x8*)(base + 2048 + kb0);
    d[3] = *(const bf16x8*)(base + 2048 + kb1);
}
// 8 B-fragment loads DIRECT from global (linear layout) into registers.
// addr(lane) = fr*128 + kg*16 (+ j*2048 + ks*64): lanes {fr,fr+16,fr+32,fr+48}
// cover one contiguous 64B line -> fully 64B-coalesced. d[ks*4+j].
__device__ __forceinline__ void loadB8(bf16x8 (&d)[8], const char* p) {
    #pragma unroll
    for (int ks = 0; ks < 2; ++ks)
        #pragma unroll
        for (int j = 0; j < 4; ++j)
            d[ks * 4 + j] = *(const bf16x8*)(p + j * 2048 + ks * 64);
}
// 16 MFMA for quadrant Q (rows [Q*32, Q*32+32) of the wave tile)
template<int Q>
__device__ __forceinline__ void mfq(f32x4 (&acc)[8][4], const bf16x8 (&a)[4],
                                    const bf16x8 (&b)[8]) {
    #pragma unroll
    for (int mf = 0; mf < 2; ++mf)
        #pragma unroll
        for (int ks = 0; ks < 2; ++ks)
            #pragma unroll
            for (int j = 0; j < 4; ++j)
                acc[2 * Q + mf][j] = __builtin_amdgcn_mfma_f32_16x16x32_bf16(
                    a[mf * 2 + ks], b[ks * 4 + j], acc[2 * Q + mf][j], 0, 0, 0);
}

// ---------------- kernel 1: pack A=[x|h] (swizzled), B gate-interleaved
// (LINEAR now -- B is consumed by direct global loads, no LDS, no swizzle) --
__global__ void pack_kernel(const float* __restrict__ x, const float* __restrict__ h,
                            const float* __restrict__ Wix, const float* __restrict__ Wfx,
                            const float* __restrict__ Wgx, const float* __restrict__ Wox,
                            const float* __restrict__ Wih, const float* __restrict__ Wfh,
                            const float* __restrict__ Wgh, const float* __restrict__ Woh,
                            uint4* __restrict__ Apk, uint4* __restrict__ Bpk)
{
    int t = blockIdx.x * blockDim.x + threadIdx.x;     // 0 .. 2M-1
    const int NCHUNK = (BATCH * K_DIM) / 8;            // 1,048,576 chunks / matrix
    bool isB = t >= NCHUNK;
    int ci = isB ? (t - NCHUNK) : t;

    int cb  = ci & 7;              // 16B chunk within row (8 bf16)
    int row = (ci >> 3) & 127;     // row within 128-row panel
    int kt  = (ci >> 10) & 31;     // K-tile
    int bt  = ci >> 15;            // 128-row panel index, 0..31

    int gr = bt * 128 + row;                           // global m or packed col n'
    const float* src;
    if (!isB) {
        // A: inverse XOR-swizzle baked in (LDS-staged via global_load_lds)
        int k0 = kt * BK + ((cb ^ (row & 7)) << 3);
        src = (k0 < IN_DIM) ? (x + (size_t)gr * IN_DIM + k0)
                            : (h + (size_t)gr * HS + (k0 - IN_DIM));
    } else {
        // B: LINEAR k layout (register-direct consumption)
        int k0 = kt * BK + (cb << 3);
        int q = (gr >> 4) & 3;                         // gate
        int u = ((gr >> 6) << 4) | (gr & 15);          // unit
        const float* Wq = (k0 < IN_DIM)
            ? ((q == 0) ? Wix : (q == 1) ? Wfx : (q == 2) ? Wgx : Wox)
            : ((q == 0) ? Wih : (q == 1) ? Wfh : (q == 2) ? Wgh : Woh);
        int kk = (k0 < IN_DIM) ? k0 : (k0 - IN_DIM);
        src = Wq + (size_t)u * 1024 + kk;
    }
    float4 v0 = ((const float4*)src)[0];
    float4 v1 = ((const float4*)src)[1];
    uint4 o;
    o.x = pk2(v0.x, v0.y); o.y = pk2(v0.z, v0.w);
    o.z = pk2(v1.x, v1.y); o.w = pk2(v1.z, v1.w);
    (isB ? Bpk : Apk)[ci] = o;
}

// ---------------- kernel 2: fused GEMM + LSTM gates ----------------
// 256x256 tile, 8 waves (2Mx4N). PIPE-DECOUPLED structure:
//  - B: register-direct from global (L2-resident slices), double-buffered
//    (bU/bV), issued one tile early. ZERO barriers/manual waits: the
//    compiler's per-register vmcnt covers them at first-use granularity.
//  - A: LDS (4-wave reuse), triple-buffered 3x32KB, staged 2 tiles ahead
//    via global_load_lds.
//  - ONE barrier + ONE counted vmcnt per K-tile. FIFO proof: issue order in
//    tile t is [B(t+1)x8][A(t+2)x4]; end-of-tile VMC(12) leaves exactly
//    those 12 => A(t+1) (issued in t-1) drained; BAR globalizes it. Tile 30:
//    VMC(8) drains A(31). WAR: A(t+2)->buf[(t+2)%3]=buf[(t-1)%3], dead since
//    the t-1/t barrier (all reads of it completed before that barrier).
__global__ void __launch_bounds__(512, 2)
gemm_kernel(const char* __restrict__ Apk, const char* __restrict__ Bpk,
            const float* __restrict__ c,
            const float* __restrict__ bix, const float* __restrict__ bfx,
            const float* __restrict__ bgx, const float* __restrict__ box_,
            const float* __restrict__ bih, const float* __restrict__ bfh,
            const float* __restrict__ bgh, const float* __restrict__ boh,
            float* __restrict__ out)
{
    __shared__ uint4 lds4[98304 / 16];                 // 96 KiB: 3 x 32KB A bufs
    char* lds = (char*)lds4;

    const int tid  = threadIdx.x;
    const int lane = tid & 63;
    const int wid  = tid >> 6;       // 0..7
    const int wm   = wid >> 2;       // 0..1
    const int wn   = wid & 3;        // 0..3
    const int fr   = lane & 15;
    const int kg   = lane >> 4;

    // XCD-aware bijective swizzle: 256 blocks, 8 XCDs, 32 blocks/XCD chunk
    const int phys = blockIdx.x;
    const int virt = (phys & 7) * 32 + (phys >> 3);
    const int bn   = virt & 15;
    const int bm   = virt >> 4;

    const char* gA = Apk + (size_t)(bm * 2) * TPB_BYTES;
    // per-wave B base: panel bn*2 + (wn>>1), row (wn&1)*64 + fr, chunk kg
    const char* gBW = Bpk + (size_t)(bn * 2 + (wn >> 1)) * TPB_BYTES
                    + ((wn & 1) * 64 + fr) * 128 + kg * 16;

    // A ds_read addressing (swizzle: k-byte ^ ((row&7)<<4); row%8 == fr%8)
    const int kb0  = (kg * 16) ^ ((fr & 7) << 4);
    const int kb1  = kb0 ^ 64;
    const int aOff = wm * 16384 + fr * 128;            // + q*4096 + mf*2048

    f32x4 acc[8][4] = {};
    bf16x8 a0[4], a1[4], a2[4], a3[4], bU[8], bV[8];

    // ---- prologue: B(0)->bU (reg); A(0)->buf0, A(1)->buf1 (LDS) ----
    loadB8(bU, gBW + (size_t)0 * HALF_BYTES);
    DSB();
    stage16k(gA + (size_t)0 * HALF_BYTES,             lds + 0,             wid, lane);
    stage16k(gA + TPB_BYTES + (size_t)0 * HALF_BYTES, lds + 16384,         wid, lane);
    stage16k(gA + (size_t)1 * HALF_BYTES,             lds + 32768,         wid, lane);
    stage16k(gA + TPB_BYTES + (size_t)1 * HALF_BYTES, lds + 32768 + 16384, wid, lane);
    VMC(4);                          // A(0) landed (leaves A(1) in flight)
    BAR();

    // one K-tile: BCUR consumed; BNXT <- B(t+1); A(t+2) staged
#define GTILE(T, BCUR, BNXT, LDB, STG, VMCN)                                  \
    {                                                                         \
      const int t_ = (T);                                                     \
      char* L  = lds + (t_ % 3) * 32768;                                      \
      if (LDB) loadB8(BNXT, gBW + (size_t)(t_ + 1) * HALF_BYTES);             \
      DSB();                                                                  \
      if (STG) {                                                              \
        char* Ls = lds + ((t_ + 2) % 3) * 32768;                              \
        stage16k(gA + (size_t)(t_ + 2) * HALF_BYTES,             Ls,         wid, lane); \
        stage16k(gA + TPB_BYTES + (size_t)(t_ + 2) * HALF_BYTES, Ls + 16384, wid, lane); \
      }                                                                       \
      DSB();                                                                  \
      rdA4(a0, L + aOff,         kb0, kb1);                                   \
      rdA4(a1, L + aOff + 4096,  kb0, kb1);                                   \
      PRIO(1); mfq<0>(acc, a0, BCUR); PRIO(0);                                \
      rdA4(a2, L + aOff + 8192,  kb0, kb1);                                   \
      PRIO(1); mfq<1>(acc, a1, BCUR); PRIO(0);                                \
      rdA4(a3, L + aOff + 12288, kb0, kb1);                                   \
      PRIO(1); mfq<2>(acc, a2, BCUR); PRIO(0);                                \
      PRIO(1); mfq<3>(acc, a3, BCUR); PRIO(0);                                \
      VMC(VMCN);                                                              \
      BAR();                                                                  \
    }

    for (int t = 0; t < NKT - 2; t += 2) {
        GTILE(t,     bU, bV, true, t     + 2 < NKT, 12);
        GTILE(t + 1, bV, bU, true, t + 1 + 2 < NKT, 12);
    }
    // tile 30: load B(31), no A-stage, VMC(8) drains A(31)
    GTILE(NKT - 2, bU, bV, true, false, 8);
#undef GTILE

    // ---- tile 31 (peeled): prefetch c/biases first, then compute ----
    const int u  = bn * 64 + wn * 16 + fr;             // unit 0..1023
    const int r0 = bm * 256 + wm * 128;                // batch row base
    {
        char* L = lds + ((NKT - 1) % 3) * 32768;
        float cpre[8][4];
        #pragma unroll
        for (int ai = 0; ai < 8; ++ai) {
            const int rowb = r0 + ai * 16 + kg * 4;
            #pragma unroll
            for (int r = 0; r < 4; ++r)
                cpre[ai][r] = c[(size_t)(rowb + r) * HS + u];
        }
        const float bi = bix[u] + bih[u];
        const float bf = bfx[u] + bfh[u];
        const float bg = bgx[u] + bgh[u];
        const float bo = box_[u] + boh[u];

        rdA4(a0, L + aOff,         kb0, kb1);
        rdA4(a1, L + aOff + 4096,  kb0, kb1);
        PRIO(1); mfq<0>(acc, a0, bV); PRIO(0);
        rdA4(a2, L + aOff + 8192,  kb0, kb1);
        PRIO(1); mfq<1>(acc, a1, bV); PRIO(0);
        rdA4(a3, L + aOff + 12288, kb0, kb1);
        PRIO(1); mfq<2>(acc, a2, bV); PRIO(0);
        PRIO(1); mfq<3>(acc, a3, bV); PRIO(0);

        // ---- fused LSTM epilogue: lane holds all 4 gates of unit u ----
        float* hout = out;
        float* cout = out + (size_t)BATCH * HS;
        #pragma unroll
        for (int ai = 0; ai < 8; ++ai) {
            const int rowb = r0 + ai * 16 + kg * 4;
            #pragma unroll
            for (int r = 0; r < 4; ++r) {
                const size_t idx = (size_t)(rowb + r) * HS + u;
                float iv = sigf  (acc[ai][0][r] + bi);
                float fv = sigf  (acc[ai][1][r] + bf);
                float gv = tanhf_(acc[ai][2][r] + bg);
                float ov = sigf  (acc[ai][3][r] + bo);
                float cn = fv * cpre[ai][r] + iv * gv;
                hout[idx] = ov * tanhf_(cn);
                cout[idx] = cn;
            }
        }
    }
}

// ---------------- launcher ----------------
extern "C" void kernel_launch(void* const* d_in, const int* in_sizes, int n_in,
                              void* d_out, int out_size, void* d_ws, size_t ws_size,
                              hipStream_t stream)
{
    const float* x   = (const float*)d_in[0];
    const float* h   = (const float*)d_in[1];
    const float* c   = (const float*)d_in[2];
    const float* Wix = (const float*)d_in[3];  const float* bix = (const float*)d_in[4];
    const float* Wfx = (const float*)d_in[5];  const float* bfx = (const float*)d_in[6];
    const float* Wgx = (const float*)d_in[7];  const float* bgx = (const float*)d_in[8];
    const float* Wox = (const float*)d_in[9];  const float* box_ = (const float*)d_in[10];
    const float* Wih = (const float*)d_in[11]; const float* bih = (const float*)d_in[12];
    const float* Wfh = (const float*)d_in[13]; const float* bfh = (const float*)d_in[14];
    const float* Wgh = (const float*)d_in[15]; const float* bgh = (const float*)d_in[16];
    const float* Woh = (const float*)d_in[17]; const float* boh = (const float*)d_in[18];

    char* ws = (char*)d_ws;
    uint4* Apk = (uint4*)ws;                                   // 16 MB
    uint4* Bpk = (uint4*)(ws + (size_t)16 * 1024 * 1024);      // 16 MB

    pack_kernel<<<8192, 256, 0, stream>>>(x, h, Wix, Wfx, Wgx, Wox,
                                          Wih, Wfh, Wgh, Woh, Apk, Bpk);
    gemm_kernel<<<256, 512, 0, stream>>>((const char*)Apk, (const char*)Bpk, c,
                                         bix, bfx, bgx, box_, bih, bfh, bgh, boh,
                                         (float*)d_out);
}

// Round 11
// 95.044 us; speedup vs baseline: 1.3727x; 1.3727x over previous
//
#include <hip/hip_runtime.h>
#include <hip/hip_bf16.h>
#include <stdint.h>

// ---------------- problem constants ----------------
#define BATCH  4096
#define IN_DIM 1024
#define HS     1024
#define K_DIM  2048                 // IN + HS
#define N_DIM  4096                 // 4 gates * HS (gate-interleaved, see pack)
#define BM 256
#define BN 128
#define BK 32
#define NKT (K_DIM / BK)            // 64 K-tiles
#define A_TILE 16384                // 256 rows x 32 k x 2B
#define B_TILE 8192                 // 128 cols x 32 k x 2B
#define BUF_BYTES (A_TILE + B_TILE) // 24576 per buffer; 3 buffers = 72 KiB

typedef __bf16 bf16x8 __attribute__((ext_vector_type(8)));
typedef float  f32x4  __attribute__((ext_vector_type(4)));

// ---------------- helpers ----------------
__device__ __forceinline__ unsigned short f2bf(float f) {
    union { float f; uint32_t u; } a; a.f = f;
    uint32_t r = a.u + 0x7FFF + ((a.u >> 16) & 1);   // RNE
    return (unsigned short)(r >> 16);
}
__device__ __forceinline__ uint32_t pk2(float a, float b) {
    return (uint32_t)f2bf(a) | ((uint32_t)f2bf(b) << 16);
}

__device__ __forceinline__ void load16_lds(const void* g, void* l) {
    __builtin_amdgcn_global_load_lds(
        (const __attribute__((address_space(1))) uint32_t*)g,
        (__attribute__((address_space(3))) uint32_t*)(uintptr_t)l,
        16, 0, 0);
}

__device__ __forceinline__ float sigf(float x)  { return 1.0f / (1.0f + __expf(-x)); }
__device__ __forceinline__ float tanhf_(float x){ return 1.0f - 2.0f / (__expf(2.0f * x) + 1.0f); }

#define BAR()   __builtin_amdgcn_s_barrier()
#define DSB()   __builtin_amdgcn_sched_barrier(0)
#define PRIO(x) __builtin_amdgcn_s_setprio(x)
#define VMC(n)  asm volatile("s_waitcnt vmcnt(" #n ")" ::: "memory")

// ---------------- kernel 1: pack A=[x|h], B gate-INTERLEAVED ----------------
// New sub-tiling for BM=256/BN=128/BK=32 with 128B LDS rows:
//  A (per bm-panel, per k-tile): 16KB = 128 LDS-rows x 8 chunks(16B).
//    LDS(lr, cb) holds source chunk sc = cb ^ (lr&7);  half = sc>>2 selects
//    m = bt*256 + half*128 + lr;  k = kt*32 + (sc&3)*8.
//  B: 8KB = 64 LDS-rows x 8 chunks. half = sc>>2 selects col n' = bt*128 +
//    half*64 + lr; k likewise. Gate-interleave: packed col n' -> gate
//    q=(n'>>4)&3, unit u=((n'>>6)<<4)|(n'&15).
__global__ void pack_kernel(const float* __restrict__ x, const float* __restrict__ h,
                            const float* __restrict__ Wix, const float* __restrict__ Wfx,
                            const float* __restrict__ Wgx, const float* __restrict__ Wox,
                            const float* __restrict__ Wih, const float* __restrict__ Wfh,
                            const float* __restrict__ Wgh, const float* __restrict__ Woh,
                            uint4* __restrict__ Apk, uint4* __restrict__ Bpk)
{
    int t = blockIdx.x * blockDim.x + threadIdx.x;     // 0 .. 2M-1
    const int NCHUNK = (BATCH * K_DIM) / 8;            // 1,048,576 chunks / matrix
    bool isB = t >= NCHUNK;
    int ci = isB ? (t - NCHUNK) : t;

    const float* src;
    if (!isB) {
        int cb = ci & 7;
        int lr = (ci >> 3) & 127;
        int kt = (ci >> 10) & 63;
        int bt = ci >> 16;                             // 0..15
        int sc = cb ^ (lr & 7);
        int m  = bt * 256 + ((sc >> 2) << 7) + lr;
        int k0 = kt * 32 + (sc & 3) * 8;
        src = (k0 < IN_DIM) ? (x + (size_t)m * IN_DIM + k0)
                            : (h + (size_t)m * HS + (k0 - IN_DIM));
    } else {
        int cb = ci & 7;
        int lr = (ci >> 3) & 63;
        int kt = (ci >> 9) & 63;
        int bt = ci >> 15;                             // 0..31
        int sc = cb ^ (lr & 7);
        int np = bt * 128 + ((sc >> 2) << 6) + lr;     // packed col
        int k0 = kt * 32 + (sc & 3) * 8;
        int q  = (np >> 4) & 3;                        // gate
        int u  = ((np >> 6) << 4) | (np & 15);         // unit
        const float* Wq = (k0 < IN_DIM)
            ? ((q == 0) ? Wix : (q == 1) ? Wfx : (q == 2) ? Wgx : Wox)
            : ((q == 0) ? Wih : (q == 1) ? Wfh : (q == 2) ? Wgh : Woh);
        int kk = (k0 < IN_DIM) ? k0 : (k0 - IN_DIM);
        src = Wq + (size_t)u * 1024 + kk;
    }
    float4 v0 = ((const float4*)src)[0];
    float4 v1 = ((const float4*)src)[1];
    uint4 o;
    o.x = pk2(v0.x, v0.y); o.y = pk2(v0.z, v0.w);
    o.z = pk2(v1.x, v1.y); o.w = pk2(v1.z, v1.w);
    (isB ? Bpk : Apk)[ci] = o;
}

// ---------------- kernel 2: fused GEMM + LSTM gates ----------------
// 256x128 tile, BK=32, 8 waves (4M x 2N), wave tile 64x64, acc[4][4]=64 regs.
// TWO BLOCKS PER CU (grid 512, LDS 72KB, launch_bounds(512,4) => <=128 VGPR):
// independent barrier domains anti-phase, so one block's MFMA covers the
// other's LDS/barrier stalls -- the issue-diversity all 1-block/CU schedules
// (r2..r9) lacked. Per-tile schedule is intentionally simple:
//   [stage t+2 -> free buffer (3 vmem)] [8 ds_reads] [16 MFMA, compiler lgkm]
//   [vmcnt(3): t+1 landed, t+2 in flight] [barrier]   (vmcnt never 0 until tail)
// Triple buffer: stage target (t+2)%3 was last read in tile t-1; every
// wave's reads of it completed (register deps) before it reached BAR(t-1/t),
// and the stage is issued after that barrier => no WAR race.
__global__ void __launch_bounds__(512, 4)
gemm_kernel(const char* __restrict__ Apk, const char* __restrict__ Bpk,
            const float* __restrict__ c,
            const float* __restrict__ bix, const float* __restrict__ bfx,
            const float* __restrict__ bgx, const float* __restrict__ box_,
            const float* __restrict__ bih, const float* __restrict__ bfh,
            const float* __restrict__ bgh, const float* __restrict__ boh,
            float* __restrict__ out)
{
    __shared__ uint4 lds4[(3 * BUF_BYTES) / 16];       // 72 KiB
    char* lds = (char*)lds4;

    const int tid  = threadIdx.x;
    const int lane = tid & 63;
    const int wid  = tid >> 6;       // 0..7
    const int wm   = wid >> 1;       // 0..3  (m quarter)
    const int wn   = wid & 1;        // 0..1  (n half)
    const int fr   = lane & 15;
    const int kg   = lane >> 4;

    // XCD-aware bijective swizzle: 512 blocks, 8 XCDs, 64 blocks/XCD chunk
    const int phys = blockIdx.x;
    const int virt = (phys & 7) * 64 + (phys >> 3);
    const int bn   = virt & 31;      // 0..31 (consecutive virt share bm -> A reuse in L2)
    const int bm   = virt >> 5;      // 0..15

    const char* gAp = Apk + (size_t)bm * (NKT * A_TILE);   // 1 MB / panel
    const char* gBp = Bpk + (size_t)bn * (NKT * B_TILE);   // 512 KB / panel
    const char* gAs = gAp + tid * 16;                      // per-lane stage src
    const char* gBs = gBp + tid * 16;

    // ds_read addressing: row lr, byte = (logical_chunk*16) ^ ((lr&7)<<4)
    const int swz   = (fr & 7) << 4;
    const int aBase = (((wm & 1) * 64 + fr) * 128) + ((((wm >> 1) << 6) + kg * 16) ^ swz);
    const int bBase = A_TILE + fr * 128 + (((wn << 6) + kg * 16) ^ swz);

    f32x4 acc[4][4] = {};
    bf16x8 a0, a1, a2, a3, b0, b1, b2, b3;

    char* Lc  = lds;                  // current (t%3)
    char* Ln1 = lds + BUF_BYTES;      // t+1
    char* Ln2 = lds + 2 * BUF_BYTES;  // t+2 (stage target)

    // ---- prologue: stage tile 0 -> buf0, tile 1 -> buf1 ----
    load16_lds(gAs,                 Lc + tid * 16);
    load16_lds(gAs + 8192,          Lc + 8192 + tid * 16);
    load16_lds(gBs,                 Lc + A_TILE + tid * 16);
    load16_lds(gAs + A_TILE,        Ln1 + tid * 16);
    load16_lds(gAs + A_TILE + 8192, Ln1 + 8192 + tid * 16);
    load16_lds(gBs + B_TILE,        Ln1 + A_TILE + tid * 16);
    VMC(3);                          // tile 0 landed; tile 1 in flight
    BAR();

    for (int t = 0; t < NKT - 1; ++t) {
        if (t + 2 < NKT) {           // stage tile t+2 into the free buffer
            load16_lds(gAs + (size_t)(t + 2) * A_TILE,        Ln2 + tid * 16);
            load16_lds(gAs + (size_t)(t + 2) * A_TILE + 8192, Ln2 + 8192 + tid * 16);
            load16_lds(gBs + (size_t)(t + 2) * B_TILE,        Ln2 + A_TILE + tid * 16);
        }
        a0 = *(const bf16x8*)(Lc + aBase);
        a1 = *(const bf16x8*)(Lc + aBase + 2048);
        a2 = *(const bf16x8*)(Lc + aBase + 4096);
        a3 = *(const bf16x8*)(Lc + aBase + 6144);
        b0 = *(const bf16x8*)(Lc + bBase);
        b1 = *(const bf16x8*)(Lc + bBase + 2048);
        b2 = *(const bf16x8*)(Lc + bBase + 4096);
        b3 = *(const bf16x8*)(Lc + bBase + 6144);
        PRIO(1);
        acc[0][0] = __builtin_amdgcn_mfma_f32_16x16x32_bf16(a0, b0, acc[0][0], 0, 0, 0);
        acc[0][1] = __builtin_amdgcn_mfma_f32_16x16x32_bf16(a0, b1, acc[0][1], 0, 0, 0);
        acc[0][2] = __builtin_amdgcn_mfma_f32_16x16x32_bf16(a0, b2, acc[0][2], 0, 0, 0);
        acc[0][3] = __builtin_amdgcn_mfma_f32_16x16x32_bf16(a0, b3, acc[0][3], 0, 0, 0);
        acc[1][0] = __builtin_amdgcn_mfma_f32_16x16x32_bf16(a1, b0, acc[1][0], 0, 0, 0);
        acc[1][1] = __builtin_amdgcn_mfma_f32_16x16x32_bf16(a1, b1, acc[1][1], 0, 0, 0);
        acc[1][2] = __builtin_amdgcn_mfma_f32_16x16x32_bf16(a1, b2, acc[1][2], 0, 0, 0);
        acc[1][3] = __builtin_amdgcn_mfma_f32_16x16x32_bf16(a1, b3, acc[1][3], 0, 0, 0);
        acc[2][0] = __builtin_amdgcn_mfma_f32_16x16x32_bf16(a2, b0, acc[2][0], 0, 0, 0);
        acc[2][1] = __builtin_amdgcn_mfma_f32_16x16x32_bf16(a2, b1, acc[2][1], 0, 0, 0);
        acc[2][2] = __builtin_amdgcn_mfma_f32_16x16x32_bf16(a2, b2, acc[2][2], 0, 0, 0);
        acc[2][3] = __builtin_amdgcn_mfma_f32_16x16x32_bf16(a2, b3, acc[2][3], 0, 0, 0);
        acc[3][0] = __builtin_amdgcn_mfma_f32_16x16x32_bf16(a3, b0, acc[3][0], 0, 0, 0);
        acc[3][1] = __builtin_amdgcn_mfma_f32_16x16x32_bf16(a3, b1, acc[3][1], 0, 0, 0);
        acc[3][2] = __builtin_amdgcn_mfma_f32_16x16x32_bf16(a3, b2, acc[3][2], 0, 0, 0);
        acc[3][3] = __builtin_amdgcn_mfma_f32_16x16x32_bf16(a3, b3, acc[3][3], 0, 0, 0);
        PRIO(0);
        DSB();
        if (t < NKT - 2) VMC(3);     // t+1 landed; t+2 stays in flight
        else             VMC(0);     // tail: drain the last stage (t=NKT-2)
        BAR();
        char* tmp = Lc; Lc = Ln1; Ln1 = Ln2; Ln2 = tmp;
    }

    // ---- peeled last tile (t = NKT-1): prefetch c/biases, compute, fuse ----
    const int u  = (bn * 2 + wn) * 16 + fr;            // unit 0..1023
    const int r0 = bm * 256 + wm * 64;                 // batch row base
    {
        float cpre[4][4];
        #pragma unroll
        for (int i = 0; i < 4; ++i) {
            const int rowb = r0 + i * 16 + kg * 4;
            #pragma unroll
            for (int r = 0; r < 4; ++r)
                cpre[i][r] = c[(size_t)(rowb + r) * HS + u];
        }
        const float bi = bix[u] + bih[u];
        const float bf = bfx[u] + bfh[u];
        const float bg = bgx[u] + bgh[u];
        const float bo = box_[u] + boh[u];

        a0 = *(const bf16x8*)(Lc + aBase);
        a1 = *(const bf16x8*)(Lc + aBase + 2048);
        a2 = *(const bf16x8*)(Lc + aBase + 4096);
        a3 = *(const bf16x8*)(Lc + aBase + 6144);
        b0 = *(const bf16x8*)(Lc + bBase);
        b1 = *(const bf16x8*)(Lc + bBase + 2048);
        b2 = *(const bf16x8*)(Lc + bBase + 4096);
        b3 = *(const bf16x8*)(Lc + bBase + 6144);
        PRIO(1);
        acc[0][0] = __builtin_amdgcn_mfma_f32_16x16x32_bf16(a0, b0, acc[0][0], 0, 0, 0);
        acc[0][1] = __builtin_amdgcn_mfma_f32_16x16x32_bf16(a0, b1, acc[0][1], 0, 0, 0);
        acc[0][2] = __builtin_amdgcn_mfma_f32_16x16x32_bf16(a0, b2, acc[0][2], 0, 0, 0);
        acc[0][3] = __builtin_amdgcn_mfma_f32_16x16x32_bf16(a0, b3, acc[0][3], 0, 0, 0);
        acc[1][0] = __builtin_amdgcn_mfma_f32_16x16x32_bf16(a1, b0, acc[1][0], 0, 0, 0);
        acc[1][1] = __builtin_amdgcn_mfma_f32_16x16x32_bf16(a1, b1, acc[1][1], 0, 0, 0);
        acc[1][2] = __builtin_amdgcn_mfma_f32_16x16x32_bf16(a1, b2, acc[1][2], 0, 0, 0);
        acc[1][3] = __builtin_amdgcn_mfma_f32_16x16x32_bf16(a1, b3, acc[1][3], 0, 0, 0);
        acc[2][0] = __builtin_amdgcn_mfma_f32_16x16x32_bf16(a2, b0, acc[2][0], 0, 0, 0);
        acc[2][1] = __builtin_amdgcn_mfma_f32_16x16x32_bf16(a2, b1, acc[2][1], 0, 0, 0);
        acc[2][2] = __builtin_amdgcn_mfma_f32_16x16x32_bf16(a2, b2, acc[2][2], 0, 0, 0);
        acc[2][3] = __builtin_amdgcn_mfma_f32_16x16x32_bf16(a2, b3, acc[2][3], 0, 0, 0);
        acc[3][0] = __builtin_amdgcn_mfma_f32_16x16x32_bf16(a3, b0, acc[3][0], 0, 0, 0);
        acc[3][1] = __builtin_amdgcn_mfma_f32_16x16x32_bf16(a3, b1, acc[3][1], 0, 0, 0);
        acc[3][2] = __builtin_amdgcn_mfma_f32_16x16x32_bf16(a3, b2, acc[3][2], 0, 0, 0);
        acc[3][3] = __builtin_amdgcn_mfma_f32_16x16x32_bf16(a3, b3, acc[3][3], 0, 0, 0);
        PRIO(0);

        // ---- fused LSTM epilogue: lane holds all 4 gates of unit u ----
        float* hout = out;
        float* cout = out + (size_t)BATCH * HS;
        #pragma unroll
        for (int i = 0; i < 4; ++i) {
            const int rowb = r0 + i * 16 + kg * 4;
            #pragma unroll
            for (int r = 0; r < 4; ++r) {
                const size_t idx = (size_t)(rowb + r) * HS + u;
                float iv = sigf  (acc[i][0][r] + bi);
                float fv = sigf  (acc[i][1][r] + bf);
                float gv = tanhf_(acc[i][2][r] + bg);
                float ov = sigf  (acc[i][3][r] + bo);
                float cn = fv * cpre[i][r] + iv * gv;
                hout[idx] = ov * tanhf_(cn);
                cout[idx] = cn;
            }
        }
    }
}

// ---------------- launcher ----------------
extern "C" void kernel_launch(void* const* d_in, const int* in_sizes, int n_in,
                              void* d_out, int out_size, void* d_ws, size_t ws_size,
                              hipStream_t stream)
{
    const float* x   = (const float*)d_in[0];
    const float* h   = (const float*)d_in[1];
    const float* c   = (const float*)d_in[2];
    const float* Wix = (const float*)d_in[3];  const float* bix = (const float*)d_in[4];
    const float* Wfx = (const float*)d_in[5];  const float* bfx = (const float*)d_in[6];
    const float* Wgx = (const float*)d_in[7];  const float* bgx = (const float*)d_in[8];
    const float* Wox = (const float*)d_in[9];  const float* box_ = (const float*)d_in[10];
    const float* Wih = (const float*)d_in[11]; const float* bih = (const float*)d_in[12];
    const float* Wfh = (const float*)d_in[13]; const float* bfh = (const float*)d_in[14];
    const float* Wgh = (const float*)d_in[15]; const float* bgh = (const float*)d_in[16];
    const float* Woh = (const float*)d_in[17]; const float* boh = (const float*)d_in[18];

    char* ws = (char*)d_ws;
    uint4* Apk = (uint4*)ws;                                   // 16 MB
    uint4* Bpk = (uint4*)(ws + (size_t)16 * 1024 * 1024);      // 16 MB

    pack_kernel<<<8192, 256, 0, stream>>>(x, h, Wix, Wfx, Wgx, Wox,
                                          Wih, Wfh, Wgh, Woh, Apk, Bpk);
    gemm_kernel<<<512, 512, 0, stream>>>((const char*)Apk, (const char*)Bpk, c,
                                         bix, bfx, bgx, box_, bih, bfh, bgh, boh,
                                         (float*)d_out);
}